// Round 1
// baseline (731.934 us; speedup 1.0000x reference)
//
#include <hip/hip_runtime.h>
#include <hip/hip_bf16.h>

typedef __attribute__((ext_vector_type(8))) short bfrag8;
typedef __attribute__((ext_vector_type(4))) float f32x4;
typedef __attribute__((ext_vector_type(4))) unsigned int u32x4;

__device__ __forceinline__ unsigned short f2bf(float x) {
  union { float f; unsigned u; } v; v.f = x;
  unsigned r = v.u + 0x7fffu + ((v.u >> 16) & 1u);
  return (unsigned short)(r >> 16);
}

// ---------------- prep: convert weights to bf16, precompute gaussian params ----
__global__ void prep_kernel(const float* __restrict__ means, const float* __restrict__ stds,
                            const float* __restrict__ W1, const float* __restrict__ W2,
                            unsigned short* __restrict__ W1bf, unsigned short* __restrict__ W2bf,
                            float* __restrict__ prm /* [3][512]: mean, istd, coef */) {
  int t = blockIdx.x * blockDim.x + threadIdx.x;
  int stride = gridDim.x * blockDim.x;
  for (int i = t; i < 512 * 512; i += stride) W1bf[i] = f2bf(W1[i]);
  for (int i = t; i < 32 * 512; i += stride) W2bf[i] = f2bf(W2[i]);
  for (int i = t; i < 512; i += stride) {
    float s = fabsf(stds[i]) + 0.01f;
    prm[i] = means[i];
    prm[512 + i] = 1.0f / s;
    prm[1024 + i] = 1.0f / (2.5066268f * s);  // 1/(sqrt(2*3.14159)*std)
  }
}

// ---------------- fused main kernel ------------------------------------------
// block: 512 threads = 8 waves, handles 64 consecutive flat rows (b,m,n).
// LDS gbuf[64][512] bf16, XOR-swizzled: byte = row*1024 + (colbyte ^ ((row&7)<<4))
__global__ __launch_bounds__(512) void fused_kernel(
    const float* __restrict__ rpe, const unsigned short* __restrict__ W1bf,
    const unsigned short* __restrict__ W2bf, const float* __restrict__ prm,
    const float* __restrict__ b1, const float* __restrict__ b2,
    float* __restrict__ out) {
  __shared__ unsigned short gbuf[64 * 512];   // 64 KB (g, then reused for h)
  __shared__ float rpe_s[64][4];              // 1 KB
  __shared__ float prm_s[3 * 512];            // 6 KB
  __shared__ float outbuf[64][33];            // 8.4 KB (padded: stride 33)

  const int tid = threadIdx.x;
  const int rb = blockIdx.x * 64;             // flat row base

  // ---- stage rpe rows + gaussian params
  if (tid < 256) ((float*)rpe_s)[tid] = rpe[rb * 4 + tid];
  for (int i = tid; i < 3 * 512; i += 512) prm_s[i] = prm[i];
  __syncthreads();

  // ---- compute g -> gbuf (bf16, swizzled). 64 rows x 64 chunks of 8 elems.
  for (int it = 0; it < 8; ++it) {
    int c = tid + it * 512;          // 0..4095
    int row = c >> 6;
    int k0 = (c & 63) * 8;           // element base, 8 consecutive k (same r)
    int r = k0 >> 7;
    float x = rpe_s[row][r];
    unsigned pk[4];
#pragma unroll
    for (int p = 0; p < 4; ++p) {
      int k = k0 + 2 * p;
      float t0 = (x - prm_s[k]) * prm_s[512 + k];
      float t1 = (x - prm_s[k + 1]) * prm_s[512 + k + 1];
      float g0 = prm_s[1024 + k] * __expf(-0.5f * t0 * t0);
      float g1 = prm_s[1024 + k + 1] * __expf(-0.5f * t1 * t1);
      pk[p] = (unsigned)f2bf(g0) | ((unsigned)f2bf(g1) << 16);
    }
    u32x4 pv = {pk[0], pk[1], pk[2], pk[3]};
    int byte = row * 1024 + ((k0 * 2) ^ ((row & 7) << 4));
    *reinterpret_cast<u32x4*>((char*)gbuf + byte) = pv;
  }
  __syncthreads();

  // ---- GEMM1: h[64][512] = g[64][512] @ W1^T, wave grid 2(M) x 4(N)
  const int w = tid >> 6, l = tid & 63;
  const int lr = l & 15, lg = l >> 4;
  const int mw = w >> 2, nw = w & 3;

  f32x4 zv = {0.f, 0.f, 0.f, 0.f};
  f32x4 acc[2][8];
#pragma unroll
  for (int mf = 0; mf < 2; ++mf)
#pragma unroll
    for (int nf = 0; nf < 8; ++nf) acc[mf][nf] = zv;

  for (int kb = 0; kb < 16; ++kb) {
    bfrag8 a[2];
#pragma unroll
    for (int mf = 0; mf < 2; ++mf) {
      int row = mw * 32 + mf * 16 + lr;
      int cb = (kb * 64 + lg * 16) ^ ((row & 7) << 4);
      a[mf] = *reinterpret_cast<const bfrag8*>((char*)gbuf + row * 1024 + cb);
    }
    int k = kb * 32 + lg * 8;
#pragma unroll
    for (int nf = 0; nf < 8; ++nf) {
      int j = nw * 128 + nf * 16 + lr;
      bfrag8 bfr = *reinterpret_cast<const bfrag8*>(W1bf + j * 512 + k);
      acc[0][nf] = __builtin_amdgcn_mfma_f32_16x16x32_bf16(a[0], bfr, acc[0][nf], 0, 0, 0);
      acc[1][nf] = __builtin_amdgcn_mfma_f32_16x16x32_bf16(a[1], bfr, acc[1][nf], 0, 0, 0);
    }
  }
  __syncthreads();   // everyone done reading g before overwriting with h

  // ---- bias + exact GELU, write h back to gbuf (same swizzled layout)
#pragma unroll
  for (int nf = 0; nf < 8; ++nf) {
    int col = nw * 128 + nf * 16 + lr;
    float bb = b1[col];
#pragma unroll
    for (int mf = 0; mf < 2; ++mf) {
#pragma unroll
      for (int bi = 0; bi < 4; ++bi) {
        float xv = acc[mf][nf][bi] + bb;
        float h = 0.5f * xv * (1.0f + erff(xv * 0.70710678f));
        int row = mw * 32 + mf * 16 + lg * 4 + bi;
        int byte = row * 1024 + ((col * 2) ^ ((row & 7) << 4));
        *reinterpret_cast<unsigned short*>((char*)gbuf + byte) = f2bf(h);
      }
    }
  }
  __syncthreads();

  // ---- GEMM2: out[64][32] = h[64][512] @ W2^T. 8 waves: 4(M) x 2(N) tiles.
  const int mf2 = w >> 1, nf2 = w & 1;
  f32x4 acc2 = zv;
  for (int kb = 0; kb < 16; ++kb) {
    int row = mf2 * 16 + lr;
    int cb = (kb * 64 + lg * 16) ^ ((row & 7) << 4);
    bfrag8 a = *reinterpret_cast<const bfrag8*>((char*)gbuf + row * 1024 + cb);
    int k = kb * 32 + lg * 8;
    bfrag8 bfr = *reinterpret_cast<const bfrag8*>(W2bf + (nf2 * 16 + lr) * 512 + k);
    acc2 = __builtin_amdgcn_mfma_f32_16x16x32_bf16(a, bfr, acc2, 0, 0, 0);
  }
  float b2v = b2[nf2 * 16 + lr];
#pragma unroll
  for (int bi = 0; bi < 4; ++bi)
    outbuf[mf2 * 16 + lg * 4 + bi][nf2 * 16 + lr] = acc2[bi] + b2v;
  __syncthreads();

  // ---- store transposed: out[b][o][m][n], 64 contiguous n per (o)
  const int bI = rb >> 16, mI = (rb >> 8) & 255, n0 = rb & 255;
  float* obase = out + ((size_t)(bI * 32) * 256 + mI) * 256 + n0;
#pragma unroll
  for (int p = 0; p < 4; ++p) {
    int e = tid + p * 512;           // 0..2047
    int o = e >> 6, i = e & 63;
    obase[(size_t)o * 65536 + i] = outbuf[i][o];
  }
}

// ---------------- launch ------------------------------------------------------
extern "C" void kernel_launch(void* const* d_in, const int* in_sizes, int n_in,
                              void* d_out, int out_size, void* d_ws, size_t ws_size,
                              hipStream_t stream) {
  const float* rpe   = (const float*)d_in[0];
  const float* means = (const float*)d_in[1];
  const float* stds  = (const float*)d_in[2];
  const float* W1    = (const float*)d_in[3];
  const float* b1    = (const float*)d_in[4];
  const float* W2    = (const float*)d_in[5];
  const float* b2    = (const float*)d_in[6];
  float* out = (float*)d_out;

  char* ws = (char*)d_ws;
  unsigned short* W1bf = (unsigned short*)ws;             // 512*512*2 = 524288 B
  unsigned short* W2bf = (unsigned short*)(ws + 524288);  // 32*512*2  =  32768 B
  float* prm = (float*)(ws + 557056);                     // 3*512*4   =   6144 B

  prep_kernel<<<256, 256, 0, stream>>>(means, stds, W1, W2, W1bf, W2bf, prm);
  fused_kernel<<<4096, 512, 0, stream>>>(rpe, W1bf, W2bf, prm, b1, b2, out);
}